// Round 2
// baseline (1486.760 us; speedup 1.0000x reference)
//
#include <hip/hip_runtime.h>
#include <stdint.h>

#define NVERT 200000
#define NTET  1000000
#define NEMAX (NTET*6)
#define NG 1000
#define KB 18
#define KMASK ((1u<<KB)-1u)

#define SCAN_T 256
#define SCAN_E 16
#define SCAN_EPB (SCAN_T*SCAN_E)   // 4096

__constant__ int c_tri[16][6] = {
  {-1,-1,-1,-1,-1,-1},{1,0,2,-1,-1,-1},{4,0,3,-1,-1,-1},{1,4,2,1,3,4},
  {3,1,5,-1,-1,-1},{2,3,0,2,5,3},{1,4,0,1,5,4},{4,2,5,-1,-1,-1},
  {4,5,2,-1,-1,-1},{4,1,0,4,5,1},{3,2,0,3,5,2},{1,3,5,-1,-1,-1},
  {4,1,2,4,3,1},{3,0,4,-1,-1,-1},{2,0,1,-1,-1,-1},{-1,-1,-1,-1,-1,-1}};
__constant__ int c_ntri[16] = {0,1,1,2,1,2,2,1,1,2,2,1,2,1,1,0};
__constant__ int c_e0[6] = {0,0,0,1,1,2};
__constant__ int c_e1[6] = {1,2,3,2,3,3};

// zero bincl + fill in one launch
__global__ void k_zero2(uint32_t* __restrict__ a, uint32_t* __restrict__ b, int n){
  int i = blockIdx.x*blockDim.x + threadIdx.x;
  if (i < n){ a[i] = 0u; b[i] = 0u; }
}

// sdf = sign*|abs|, occ = sdf > 0
__global__ void k_sdf(const float* __restrict__ ssign, const float* __restrict__ sabs,
                      float* __restrict__ sdf, uint8_t* __restrict__ occ){
  int i = blockIdx.x*blockDim.x + threadIdx.x;
  if (i >= NVERT) return;
  float s = ssign[i] * fabsf(sabs[i]);
  sdf[i] = s;
  occ[i] = (s > 0.0f) ? 1 : 0;
}

// per-tet: tetindex, one/two flags, bucket counts for valid tets' 6 edges
__global__ void k_tet(const int* __restrict__ idx, const uint8_t* __restrict__ occ,
                      uint8_t* __restrict__ tetidx, uint32_t* __restrict__ oneA,
                      uint32_t* __restrict__ twoA, uint32_t* __restrict__ bcnt){
  int t = blockIdx.x*blockDim.x + threadIdx.x;
  if (t >= NTET) return;
  int v[4];
  #pragma unroll
  for (int j = 0; j < 4; ++j) v[j] = idx[t*4+j];
  int ti = 0;
  #pragma unroll
  for (int j = 0; j < 4; ++j) ti |= (occ[v[j]] ? 1 : 0) << j;
  tetidx[t] = (uint8_t)ti;
  int nt = c_ntri[ti];
  oneA[t] = (nt == 1) ? 1u : 0u;
  twoA[t] = (nt == 2) ? 1u : 0u;
  if (nt == 0) return;
  #pragma unroll
  for (int e = 0; e < 6; ++e){
    int a = v[c_e0[e]], b = v[c_e1[e]];
    if (a > b){ int tmp = a; a = b; b = tmp; }
    atomicAdd((unsigned int*)&bcnt[a], 1u);
  }
}

// ---- generic in-place inclusive scan over u32 ----
__global__ void k_scan_block(uint32_t* __restrict__ d, uint32_t* __restrict__ part, int L){
  int tid = threadIdx.x;
  int base = blockIdx.x*SCAN_EPB + tid*SCAN_E;
  uint32_t v[SCAN_E];
  #pragma unroll
  for (int j = 0; j < SCAN_E; ++j){
    int i = base + j;
    v[j] = (i < L) ? d[i] : 0u;
  }
  #pragma unroll
  for (int j = 1; j < SCAN_E; ++j) v[j] += v[j-1];
  __shared__ uint32_t s[SCAN_T];
  s[tid] = v[SCAN_E-1];
  __syncthreads();
  for (int o = 1; o < SCAN_T; o <<= 1){
    uint32_t x = (tid >= o) ? s[tid-o] : 0u;
    __syncthreads();
    s[tid] += x;
    __syncthreads();
  }
  uint32_t off = s[tid] - v[SCAN_E-1];   // exclusive prefix of this thread
  #pragma unroll
  for (int j = 0; j < SCAN_E; ++j){
    int i = base + j;
    if (i < L) d[i] = v[j] + off;
  }
  if (tid == SCAN_T-1 && part) part[blockIdx.x] = s[SCAN_T-1];
}

__global__ void k_scan_part(uint32_t* __restrict__ part, int n){
  int tid = threadIdx.x;
  int per = (n + SCAN_T - 1)/SCAN_T;
  int st = tid*per, en = st + per; if (en > n) en = n;
  uint32_t sum = 0;
  for (int i = st; i < en; ++i) sum += part[i];
  __shared__ uint32_t s[SCAN_T];
  s[tid] = sum;
  __syncthreads();
  for (int o = 1; o < SCAN_T; o <<= 1){
    uint32_t x = (tid >= o) ? s[tid-o] : 0u;
    __syncthreads();
    s[tid] += x;
    __syncthreads();
  }
  uint32_t off = s[tid] - sum;
  uint32_t run = off;
  for (int i = st; i < en; ++i){ run += part[i]; part[i] = run; }
}

__global__ void k_scan_add(uint32_t* __restrict__ d, const uint32_t* __restrict__ part, int L){
  int blk = blockIdx.x;
  if (blk == 0) return;
  uint32_t off = part[blk-1];
  int base = blk*SCAN_EPB;
  #pragma unroll
  for (int j = 0; j < SCAN_E; ++j){
    int i = base + j*SCAN_T + threadIdx.x;
    if (i < L) d[i] += off;
  }
}

// scatter edge keys into buckets (bincl = inclusive scan of counts)
__global__ void k_scatter(const int* __restrict__ idx, const uint8_t* __restrict__ tetidx,
                          const uint32_t* __restrict__ bincl, uint32_t* __restrict__ fill,
                          uint64_t* __restrict__ skey){
  int t = blockIdx.x*blockDim.x + threadIdx.x;
  if (t >= NTET) return;
  int ti = tetidx[t];
  if (c_ntri[ti] == 0) return;
  int v[4];
  #pragma unroll
  for (int j = 0; j < 4; ++j) v[j] = idx[t*4+j];
  #pragma unroll
  for (int e = 0; e < 6; ++e){
    int a = v[c_e0[e]], b = v[c_e1[e]];
    if (a > b){ int tmp = a; a = b; b = tmp; }
    uint32_t base = (a > 0) ? bincl[a-1] : 0u;
    uint32_t p = base + atomicAdd((unsigned int*)&fill[a], 1u);
    skey[p] = ((uint64_t)(uint32_t)a << KB) | (uint32_t)b;
  }
}

// per-bucket sort (rank sort in LDS); buckets are tiny (λ≈26..52)
__global__ void __launch_bounds__(64) k_bsort(uint64_t* __restrict__ skey,
                                              const uint32_t* __restrict__ bincl){
  int b = blockIdx.x;
  uint32_t s0 = (b > 0) ? bincl[b-1] : 0u;
  uint32_t e0 = bincl[b];
  int n = (int)(e0 - s0);
  if (n <= 1) return;
  if (n <= 1024){
    __shared__ uint64_t sk[1024];
    for (int i = threadIdx.x; i < n; i += 64) sk[i] = skey[s0+i];
    __syncthreads();
    for (int i = threadIdx.x; i < n; i += 64){
      uint64_t ki = sk[i];
      int r = 0;
      for (int j = 0; j < n; ++j){
        uint64_t kj = sk[j];
        if (kj < ki || (kj == ki && j < i)) ++r;
      }
      skey[s0 + r] = ki;
    }
  } else if (threadIdx.x == 0){
    // pathological fallback (never expected): insertion sort in global mem
    for (int i = 1; i < n; ++i){
      uint64_t x = skey[s0+i];
      int j = i-1;
      while (j >= 0 && skey[s0+j] > x){ skey[s0+j+1] = skey[s0+j]; --j; }
      skey[s0+j+1] = x;
    }
  }
}

// flag = (first occurrence of key) && (edge crosses surface)
__global__ void k_flags(const uint64_t* __restrict__ skey, const uint8_t* __restrict__ occ,
                        const uint32_t* __restrict__ bincl, uint32_t* __restrict__ maskA){
  int i = blockIdx.x*blockDim.x + threadIdx.x;
  if (i >= NEMAX) return;
  uint32_t nE = bincl[NVERT-1];
  if ((uint32_t)i >= nE){ maskA[i] = 0u; return; }
  uint64_t k = skey[i];
  bool head = (i == 0) || (skey[i-1] != k);
  uint32_t a = (uint32_t)(k >> KB), b = (uint32_t)(k & KMASK);
  maskA[i] = (head && (occ[a] != occ[b])) ? 1u : 0u;
}

// write out_verts rows (rank = inclusive mask scan - 1)
__global__ void k_verts(const uint64_t* __restrict__ skey, const uint32_t* __restrict__ maskI,
                        const uint32_t* __restrict__ bincl,
                        const float* __restrict__ verts, const float* __restrict__ deform,
                        const float* __restrict__ sdf, float* __restrict__ out){
  int i = blockIdx.x*blockDim.x + threadIdx.x;
  if (i >= NEMAX) return;
  uint32_t nE = bincl[NVERT-1];
  if ((uint32_t)i >= nE) return;
  uint32_t m = maskI[i];
  uint32_t pm = (i > 0) ? maskI[i-1] : 0u;
  if (m == pm) return;           // not a masked head
  m -= 1u;
  uint64_t k = skey[i];
  int a = (int)(k >> KB), b = (int)(k & KMASK);
  float sa = sdf[a], sb = sdf[b];
  float denom = sa - sb;
  float w0 = __fdiv_rn(-sb, denom);
  float w1 = __fdiv_rn(sa, denom);
  #pragma unroll
  for (int c = 0; c < 3; ++c){
    float pa = __fadd_rn(verts[a*3+c], __fmul_rn(0.0078125f, deform[a*3+c]));
    float pb = __fadd_rn(verts[b*3+c], __fmul_rn(0.0078125f, deform[b*3+c]));
    out[(size_t)m*3 + c] = __fadd_rn(__fmul_rn(pa, w0), __fmul_rn(pb, w1));
  }
}

// faces + uv_idx
__global__ void k_faces(const int* __restrict__ idx, const uint8_t* __restrict__ tetidx,
                        const uint32_t* __restrict__ oneI, const uint32_t* __restrict__ twoI,
                        const uint32_t* __restrict__ maskI, const uint32_t* __restrict__ bincl,
                        const uint64_t* __restrict__ skey, float* __restrict__ out){
  int t = blockIdx.x*blockDim.x + threadIdx.x;
  if (t >= NTET) return;
  int ti = tetidx[t];
  int nt = c_ntri[ti];
  if (nt == 0) return;
  // wave-uniform totals: read once, broadcast via readfirstlane
  uint32_t nE      = (uint32_t)__builtin_amdgcn_readfirstlane((int)bincl[NVERT-1]);
  uint32_t nInterp = (uint32_t)__builtin_amdgcn_readfirstlane((int)maskI[NEMAX-1]);
  uint32_t nOne    = (uint32_t)__builtin_amdgcn_readfirstlane((int)oneI[NTET-1]);
  uint32_t nTwo    = (uint32_t)__builtin_amdgcn_readfirstlane((int)twoI[NTET-1]);
  size_t facesOff = (size_t)3*nInterp;
  size_t nFaces = (size_t)nOne + 2u*(size_t)nTwo;
  size_t uvIdxOff = facesOff + 3*nFaces + (size_t)(4*NG*NG)*2;
  int v[4];
  #pragma unroll
  for (int j = 0; j < 4; ++j) v[j] = idx[t*4+j];
  for (int k = 0; k < nt; ++k){
    size_t row = (nt == 1) ? (size_t)(oneI[t]-1u)
                           : (size_t)nOne + 2u*(size_t)(twoI[t]-1u) + (size_t)k;
    #pragma unroll
    for (int j = 0; j < 3; ++j){
      int e = c_tri[ti][k*3+j];
      int a = v[c_e0[e]], b = v[c_e1[e]];
      if (a > b){ int tmp = a; a = b; b = tmp; }
      uint64_t key = ((uint64_t)(uint32_t)a << KB) | (uint32_t)b;
      uint32_t lo = 0, hi = nE;
      while (lo < hi){
        uint32_t mid = (lo + hi) >> 1;
        if (skey[mid] < key) lo = mid + 1; else hi = mid;
      }
      out[facesOff + row*3 + j] = (float)(maskI[lo] - 1u);
    }
    int tri = (nt == 2) ? k : 0;
    long long t4 = 4LL*t;
    out[uvIdxOff + row*3 + 0] = (float)t4;
    out[uvIdxOff + row*3 + 1] = (float)(t4 + tri + 1);
    out[uvIdxOff + row*3 + 2] = (float)(t4 + tri + 2);
  }
}

// fixed UV grid (numpy linspace float64 semantics, cast to f32)
__global__ void k_uvs(const uint32_t* __restrict__ maskI, const uint32_t* __restrict__ oneI,
                      const uint32_t* __restrict__ twoI, float* __restrict__ out){
  int r = blockIdx.x*blockDim.x + threadIdx.x;
  if (r >= 4*NG*NG) return;
  uint32_t nInterp = (uint32_t)__builtin_amdgcn_readfirstlane((int)maskI[NEMAX-1]);
  uint32_t nOne    = (uint32_t)__builtin_amdgcn_readfirstlane((int)oneI[NTET-1]);
  uint32_t nTwo    = (uint32_t)__builtin_amdgcn_readfirstlane((int)twoI[NTET-1]);
  size_t uvOff = (size_t)3*nInterp + 3*((size_t)nOne + 2u*(size_t)nTwo);
  int cell = r >> 2, c = r & 3;
  int iy = cell / NG, jx = cell % NG;
  const double step = (1.0 - 1.0/NG)/(NG-1);
  float x = (jx == NG-1) ? (float)(1.0 - 1.0/NG) : (float)((double)jx*step);
  float y = (iy == NG-1) ? (float)(1.0 - 1.0/NG) : (float)((double)iy*step);
  float pad = (float)(0.9/NG);
  float u, vv;
  switch (c){
    case 0: u = x;                      vv = y;                      break;
    case 1: u = __fadd_rn(x, pad);      vv = y;                      break;
    case 2: u = __fadd_rn(x, pad);      vv = __fadd_rn(y, pad);      break;
    default:u = x;                      vv = __fadd_rn(y, pad);      break;
  }
  out[uvOff + (size_t)r*2 + 0] = u;
  out[uvOff + (size_t)r*2 + 1] = vv;
}

static void scan_u32(uint32_t* d, int L, uint32_t* part, hipStream_t s){
  int nb = (L + SCAN_EPB - 1)/SCAN_EPB;
  k_scan_block<<<nb, SCAN_T, 0, s>>>(d, part, L);
  if (nb > 1){
    k_scan_part<<<1, SCAN_T, 0, s>>>(part, nb);
    k_scan_add<<<nb, SCAN_T, 0, s>>>(d, part, L);
  }
}

extern "C" void kernel_launch(void* const* d_in, const int* in_sizes, int n_in,
                              void* d_out, int out_size, void* d_ws, size_t ws_size,
                              hipStream_t stream){
  const float* verts  = (const float*)d_in[0];
  const float* deform = (const float*)d_in[1];
  const float* ssign  = (const float*)d_in[2];
  const float* sabs   = (const float*)d_in[3];
  const int*   idx    = (const int*)d_in[4];
  float* out = (float*)d_out;

  char* ws = (char*)d_ws;
  size_t o = 0;
  auto alloc = [&](size_t bytes) -> void* {
    void* p = ws + o;
    o = (o + bytes + 255) & ~(size_t)255;
    return p;
  };
  float*    sdf    = (float*)   alloc(sizeof(float)*NVERT);
  uint8_t*  occ    = (uint8_t*) alloc(NVERT);
  uint8_t*  tetidx = (uint8_t*) alloc(NTET);
  uint32_t* bincl  = (uint32_t*)alloc(sizeof(uint32_t)*NVERT);
  uint32_t* fill   = (uint32_t*)alloc(sizeof(uint32_t)*NVERT);
  uint32_t* oneI   = (uint32_t*)alloc(sizeof(uint32_t)*NTET);
  uint32_t* twoI   = (uint32_t*)alloc(sizeof(uint32_t)*NTET);
  uint32_t* maskI  = (uint32_t*)alloc(sizeof(uint32_t)*NEMAX);
  uint64_t* skey   = (uint64_t*)alloc(sizeof(uint64_t)*NEMAX);
  uint32_t* part   = (uint32_t*)alloc(sizeof(uint32_t)*2048);
  if (o > ws_size) return;  // workspace too small: bail loudly (validation fails)

  k_zero2<<<(NVERT+255)/256, 256, 0, stream>>>(bincl, fill, NVERT);

  k_sdf<<<(NVERT+255)/256, 256, 0, stream>>>(ssign, sabs, sdf, occ);
  k_tet<<<(NTET+255)/256, 256, 0, stream>>>(idx, occ, tetidx, oneI, twoI, bincl);

  scan_u32(bincl, NVERT, part, stream);

  k_scatter<<<(NTET+255)/256, 256, 0, stream>>>(idx, tetidx, bincl, fill, skey);
  k_bsort<<<NVERT, 64, 0, stream>>>(skey, bincl);

  k_flags<<<(NEMAX+255)/256, 256, 0, stream>>>(skey, occ, bincl, maskI);
  scan_u32(maskI, NEMAX, part, stream);
  scan_u32(oneI, NTET, part, stream);
  scan_u32(twoI, NTET, part, stream);

  k_verts<<<(NEMAX+255)/256, 256, 0, stream>>>(skey, maskI, bincl, verts, deform, sdf, out);
  k_faces<<<(NTET+255)/256, 256, 0, stream>>>(idx, tetidx, oneI, twoI, maskI, bincl, skey, out);
  k_uvs<<<(4*NG*NG+255)/256, 256, 0, stream>>>(maskI, oneI, twoI, out);
}

// Round 3
// 690.371 us; speedup vs baseline: 2.1536x; 2.1536x over previous
//
#include <hip/hip_runtime.h>
#include <stdint.h>

#define NVERT 200000
#define NTET  1000000
#define NE2   4000000          // capacity for CROSSING edge instances (expected ~2.63M, seed-0)
#define NG 1000
#define PAYB 23
#define PAYMASK ((1u<<PAYB)-1u)
#define KB 18
#define KMASK ((1u<<KB)-1u)

#define SCAN_T 256
#define SCAN_E 16
#define SCAN_EPB (SCAN_T*SCAN_E)   // 4096

__constant__ int c_tri[16][6] = {
  {-1,-1,-1,-1,-1,-1},{1,0,2,-1,-1,-1},{4,0,3,-1,-1,-1},{1,4,2,1,3,4},
  {3,1,5,-1,-1,-1},{2,3,0,2,5,3},{1,4,0,1,5,4},{4,2,5,-1,-1,-1},
  {4,5,2,-1,-1,-1},{4,1,0,4,5,1},{3,2,0,3,5,2},{1,3,5,-1,-1,-1},
  {4,1,2,4,3,1},{3,0,4,-1,-1,-1},{2,0,1,-1,-1,-1},{-1,-1,-1,-1,-1,-1}};
__constant__ int c_ntri[16] = {0,1,1,2,1,2,2,1,1,2,2,1,2,1,1,0};
__constant__ int c_e0[6] = {0,0,0,1,1,2};
__constant__ int c_e1[6] = {1,2,3,2,3,3};

__global__ void k_zero2(uint32_t* __restrict__ a, uint32_t* __restrict__ b, int n){
  int i = blockIdx.x*blockDim.x + threadIdx.x;
  if (i < n){ a[i] = 0u; b[i] = 0u; }
}

// sdf = sign*|abs|, occ = sdf > 0
__global__ void k_sdf(const float* __restrict__ ssign, const float* __restrict__ sabs,
                      float* __restrict__ sdf, uint8_t* __restrict__ occ){
  int i = blockIdx.x*blockDim.x + threadIdx.x;
  if (i >= NVERT) return;
  float s = ssign[i] * fabsf(sabs[i]);
  sdf[i] = s;
  occ[i] = (s > 0.0f) ? 1 : 0;
}

// per-tet: tetindex, one/two flags, bucket counts for CROSSING edges only
__global__ void k_tet(const int* __restrict__ idx, const uint8_t* __restrict__ occ,
                      uint8_t* __restrict__ tetidx, uint32_t* __restrict__ oneA,
                      uint32_t* __restrict__ twoA, uint32_t* __restrict__ bcnt){
  int t = blockIdx.x*blockDim.x + threadIdx.x;
  if (t >= NTET) return;
  int v[4];
  #pragma unroll
  for (int j = 0; j < 4; ++j) v[j] = idx[t*4+j];
  int ti = 0;
  #pragma unroll
  for (int j = 0; j < 4; ++j) ti |= (occ[v[j]] ? 1 : 0) << j;
  tetidx[t] = (uint8_t)ti;
  int nt = c_ntri[ti];
  oneA[t] = (nt == 1) ? 1u : 0u;
  twoA[t] = (nt == 2) ? 1u : 0u;
  if (nt == 0) return;
  #pragma unroll
  for (int e = 0; e < 6; ++e){
    int o0 = (ti >> c_e0[e]) & 1, o1 = (ti >> c_e1[e]) & 1;
    if (o0 == o1) continue;               // only crossing edges enter the pipeline
    int a = v[c_e0[e]], b = v[c_e1[e]];
    if (a > b){ int tmp = a; a = b; b = tmp; }
    atomicAdd((unsigned int*)&bcnt[a], 1u);
  }
}

// ---- generic in-place inclusive scan over u32 ----
__global__ void k_scan_block(uint32_t* __restrict__ d, uint32_t* __restrict__ part, int L){
  int tid = threadIdx.x;
  int base = blockIdx.x*SCAN_EPB + tid*SCAN_E;
  uint32_t v[SCAN_E];
  #pragma unroll
  for (int j = 0; j < SCAN_E; ++j){
    int i = base + j;
    v[j] = (i < L) ? d[i] : 0u;
  }
  #pragma unroll
  for (int j = 1; j < SCAN_E; ++j) v[j] += v[j-1];
  __shared__ uint32_t s[SCAN_T];
  s[tid] = v[SCAN_E-1];
  __syncthreads();
  for (int o = 1; o < SCAN_T; o <<= 1){
    uint32_t x = (tid >= o) ? s[tid-o] : 0u;
    __syncthreads();
    s[tid] += x;
    __syncthreads();
  }
  uint32_t off = s[tid] - v[SCAN_E-1];
  #pragma unroll
  for (int j = 0; j < SCAN_E; ++j){
    int i = base + j;
    if (i < L) d[i] = v[j] + off;
  }
  if (tid == SCAN_T-1 && part) part[blockIdx.x] = s[SCAN_T-1];
}

__global__ void k_scan_part(uint32_t* __restrict__ part, int n){
  int tid = threadIdx.x;
  int per = (n + SCAN_T - 1)/SCAN_T;
  int st = tid*per, en = st + per; if (en > n) en = n;
  uint32_t sum = 0;
  for (int i = st; i < en; ++i) sum += part[i];
  __shared__ uint32_t s[SCAN_T];
  s[tid] = sum;
  __syncthreads();
  for (int o = 1; o < SCAN_T; o <<= 1){
    uint32_t x = (tid >= o) ? s[tid-o] : 0u;
    __syncthreads();
    s[tid] += x;
    __syncthreads();
  }
  uint32_t off = s[tid] - sum;
  uint32_t run = off;
  for (int i = st; i < en; ++i){ run += part[i]; part[i] = run; }
}

__global__ void k_scan_add(uint32_t* __restrict__ d, const uint32_t* __restrict__ part, int L){
  int blk = blockIdx.x;
  if (blk == 0) return;
  uint32_t off = part[blk-1];
  int base = blk*SCAN_EPB;
  #pragma unroll
  for (int j = 0; j < SCAN_E; ++j){
    int i = base + j*SCAN_T + threadIdx.x;
    if (i < L) d[i] += off;
  }
}

// scatter crossing-edge keys (with origin payload) into buckets
__global__ void k_scatter(const int* __restrict__ idx, const uint8_t* __restrict__ tetidx,
                          const uint32_t* __restrict__ bincl, uint32_t* __restrict__ fill,
                          uint64_t* __restrict__ skey){
  int t = blockIdx.x*blockDim.x + threadIdx.x;
  if (t >= NTET) return;
  int ti = tetidx[t];
  if (c_ntri[ti] == 0) return;
  int v[4];
  #pragma unroll
  for (int j = 0; j < 4; ++j) v[j] = idx[t*4+j];
  #pragma unroll
  for (int e = 0; e < 6; ++e){
    int o0 = (ti >> c_e0[e]) & 1, o1 = (ti >> c_e1[e]) & 1;
    if (o0 == o1) continue;
    int a = v[c_e0[e]], b = v[c_e1[e]];
    if (a > b){ int tmp = a; a = b; b = tmp; }
    uint32_t base = (a > 0) ? bincl[a-1] : 0u;
    uint32_t p = base + atomicAdd((unsigned int*)&fill[a], 1u);
    if (p < NE2)
      skey[p] = ((uint64_t)(uint32_t)a << (PAYB+KB)) | ((uint64_t)(uint32_t)b << PAYB)
              | (uint32_t)(t*6 + e);
  }
}

// persistent-wave per-bucket rank sort, all in registers via shuffle.
// keys are distinct (payload unique) -> no tie-break needed.
__global__ void k_bsort(uint64_t* __restrict__ skey, const uint32_t* __restrict__ bincl){
  int gid  = blockIdx.x*blockDim.x + threadIdx.x;
  int w    = gid >> 6;
  int lane = threadIdx.x & 63;
  int W    = (gridDim.x*blockDim.x) >> 6;
  for (int b = w; b < NVERT; b += W){
    uint32_t s0 = (b > 0) ? bincl[b-1] : 0u;
    uint32_t e0 = bincl[b];
    int n = (int)(e0 - s0);
    if (n <= 1) continue;
    if (n <= 64){
      uint64_t ki = (lane < n) ? skey[s0+lane] : ~0ull;
      int r = 0;
      for (int j = 0; j < n; ++j){
        uint64_t kj = __shfl(ki, j, 64);
        r += (kj < ki) ? 1 : 0;
      }
      if (lane < n) skey[s0 + r] = ki;
    } else if (n <= 128){
      uint64_t k0 = (lane < n)      ? skey[s0+lane]    : ~0ull;
      uint64_t k1 = (64+lane < n)   ? skey[s0+64+lane] : ~0ull;
      int r0 = 0, r1 = 0;
      for (int j = 0; j < 64; ++j){
        uint64_t kj = __shfl(k0, j, 64);
        r0 += (kj < k0) ? 1 : 0;
        r1 += (kj < k1) ? 1 : 0;
      }
      for (int j = 64; j < n; ++j){
        uint64_t kj = __shfl(k1, j-64, 64);
        r0 += (kj < k0) ? 1 : 0;
        r1 += (kj < k1) ? 1 : 0;
      }
      if (lane < n)    skey[s0 + r0] = k0;
      if (64+lane < n) skey[s0 + r1] = k1;
    } else if (lane == 0){
      // pathological fallback (never expected at seed 0)
      for (int i = 1; i < n; ++i){
        uint64_t x = skey[s0+i];
        int j = i-1;
        while (j >= 0 && skey[s0+j] > x){ skey[s0+j+1] = skey[s0+j]; --j; }
        skey[s0+j+1] = x;
      }
    }
  }
}

// flag = first occurrence of (a,b) key (all entries are crossing by construction)
__global__ void k_flags(const uint64_t* __restrict__ skey,
                        const uint32_t* __restrict__ bincl, uint32_t* __restrict__ maskA){
  int i = blockIdx.x*blockDim.x + threadIdx.x;
  if (i >= NE2) return;
  uint32_t nE = (uint32_t)__builtin_amdgcn_readfirstlane((int)bincl[NVERT-1]);
  if ((uint32_t)i >= nE){ maskA[i] = 0u; return; }
  uint64_t k = skey[i] >> PAYB;
  bool head = (i == 0) || ((skey[i-1] >> PAYB) != k);
  maskA[i] = head ? 1u : 0u;
}

// per-instance: propagate vertex rank back to origin slot; write out_verts at heads
__global__ void k_emit(const uint64_t* __restrict__ skey, const uint32_t* __restrict__ maskI,
                       const uint32_t* __restrict__ bincl,
                       const float* __restrict__ verts, const float* __restrict__ deform,
                       const float* __restrict__ sdf,
                       uint32_t* __restrict__ edge2vert, float* __restrict__ out){
  int i = blockIdx.x*blockDim.x + threadIdx.x;
  if (i >= NE2) return;
  uint32_t nE = (uint32_t)__builtin_amdgcn_readfirstlane((int)bincl[NVERT-1]);
  if ((uint32_t)i >= nE) return;
  uint64_t k = skey[i];
  uint32_t m = maskI[i];
  uint32_t pm = (i > 0) ? maskI[i-1] : 0u;
  uint32_t vid = m - 1u;
  edge2vert[(uint32_t)(k & PAYMASK)] = vid;
  if (m == pm) return;                      // duplicate instance: rank already correct
  int a = (int)(k >> (PAYB+KB)), b = (int)((k >> PAYB) & KMASK);
  float sa = sdf[a], sb = sdf[b];
  float denom = sa - sb;
  float w0 = __fdiv_rn(-sb, denom);
  float w1 = __fdiv_rn(sa, denom);
  #pragma unroll
  for (int c = 0; c < 3; ++c){
    float pa = __fadd_rn(verts[a*3+c], __fmul_rn(0.0078125f, deform[a*3+c]));
    float pb = __fadd_rn(verts[b*3+c], __fmul_rn(0.0078125f, deform[b*3+c]));
    out[(size_t)vid*3 + c] = __fadd_rn(__fmul_rn(pa, w0), __fmul_rn(pb, w1));
  }
}

// faces + uv_idx via direct edge2vert lookup (no idx read, no search)
__global__ void k_faces(const uint8_t* __restrict__ tetidx,
                        const uint32_t* __restrict__ oneI, const uint32_t* __restrict__ twoI,
                        const uint32_t* __restrict__ maskI,
                        const uint32_t* __restrict__ edge2vert, float* __restrict__ out){
  int t = blockIdx.x*blockDim.x + threadIdx.x;
  if (t >= NTET) return;
  int ti = tetidx[t];
  int nt = c_ntri[ti];
  if (nt == 0) return;
  uint32_t nInterp = (uint32_t)__builtin_amdgcn_readfirstlane((int)maskI[NE2-1]);
  uint32_t nOne    = (uint32_t)__builtin_amdgcn_readfirstlane((int)oneI[NTET-1]);
  uint32_t nTwo    = (uint32_t)__builtin_amdgcn_readfirstlane((int)twoI[NTET-1]);
  size_t facesOff = (size_t)3*nInterp;
  size_t nFaces = (size_t)nOne + 2u*(size_t)nTwo;
  size_t uvIdxOff = facesOff + 3*nFaces + (size_t)(4*NG*NG)*2;
  for (int k = 0; k < nt; ++k){
    size_t row = (nt == 1) ? (size_t)(oneI[t]-1u)
                           : (size_t)nOne + 2u*(size_t)(twoI[t]-1u) + (size_t)k;
    #pragma unroll
    for (int j = 0; j < 3; ++j){
      int e = c_tri[ti][k*3+j];
      out[facesOff + row*3 + j] = (float)edge2vert[t*6 + e];
    }
    int tri = (nt == 2) ? k : 0;
    long long t4 = 4LL*t;
    out[uvIdxOff + row*3 + 0] = (float)t4;
    out[uvIdxOff + row*3 + 1] = (float)(t4 + tri + 1);
    out[uvIdxOff + row*3 + 2] = (float)(t4 + tri + 2);
  }
}

// fixed UV grid (numpy linspace float64 semantics, cast to f32)
__global__ void k_uvs(const uint32_t* __restrict__ maskI, const uint32_t* __restrict__ oneI,
                      const uint32_t* __restrict__ twoI, float* __restrict__ out){
  int r = blockIdx.x*blockDim.x + threadIdx.x;
  if (r >= 4*NG*NG) return;
  uint32_t nInterp = (uint32_t)__builtin_amdgcn_readfirstlane((int)maskI[NE2-1]);
  uint32_t nOne    = (uint32_t)__builtin_amdgcn_readfirstlane((int)oneI[NTET-1]);
  uint32_t nTwo    = (uint32_t)__builtin_amdgcn_readfirstlane((int)twoI[NTET-1]);
  size_t uvOff = (size_t)3*nInterp + 3*((size_t)nOne + 2u*(size_t)nTwo);
  int cell = r >> 2, c = r & 3;
  int iy = cell / NG, jx = cell % NG;
  const double step = (1.0 - 1.0/NG)/(NG-1);
  float x = (jx == NG-1) ? (float)(1.0 - 1.0/NG) : (float)((double)jx*step);
  float y = (iy == NG-1) ? (float)(1.0 - 1.0/NG) : (float)((double)iy*step);
  float pad = (float)(0.9/NG);
  float u, vv;
  switch (c){
    case 0: u = x;                 vv = y;                 break;
    case 1: u = __fadd_rn(x, pad); vv = y;                 break;
    case 2: u = __fadd_rn(x, pad); vv = __fadd_rn(y, pad); break;
    default:u = x;                 vv = __fadd_rn(y, pad); break;
  }
  out[uvOff + (size_t)r*2 + 0] = u;
  out[uvOff + (size_t)r*2 + 1] = vv;
}

static void scan_u32(uint32_t* d, int L, uint32_t* part, hipStream_t s){
  int nb = (L + SCAN_EPB - 1)/SCAN_EPB;
  k_scan_block<<<nb, SCAN_T, 0, s>>>(d, part, L);
  if (nb > 1){
    k_scan_part<<<1, SCAN_T, 0, s>>>(part, nb);
    k_scan_add<<<nb, SCAN_T, 0, s>>>(d, part, L);
  }
}

extern "C" void kernel_launch(void* const* d_in, const int* in_sizes, int n_in,
                              void* d_out, int out_size, void* d_ws, size_t ws_size,
                              hipStream_t stream){
  const float* verts  = (const float*)d_in[0];
  const float* deform = (const float*)d_in[1];
  const float* ssign  = (const float*)d_in[2];
  const float* sabs   = (const float*)d_in[3];
  const int*   idx    = (const int*)d_in[4];
  float* out = (float*)d_out;

  char* ws = (char*)d_ws;
  size_t o = 0;
  auto alloc = [&](size_t bytes) -> void* {
    void* p = ws + o;
    o = (o + bytes + 255) & ~(size_t)255;
    return p;
  };
  float*    sdf     = (float*)   alloc(sizeof(float)*NVERT);
  uint8_t*  occ     = (uint8_t*) alloc(NVERT);
  uint8_t*  tetidx  = (uint8_t*) alloc(NTET);
  uint32_t* bincl   = (uint32_t*)alloc(sizeof(uint32_t)*NVERT);
  uint32_t* fill    = (uint32_t*)alloc(sizeof(uint32_t)*NVERT);
  uint32_t* oneI    = (uint32_t*)alloc(sizeof(uint32_t)*NTET);
  uint32_t* twoI    = (uint32_t*)alloc(sizeof(uint32_t)*NTET);
  uint32_t* maskI   = (uint32_t*)alloc(sizeof(uint32_t)*NE2);
  uint64_t* skey    = (uint64_t*)alloc(sizeof(uint64_t)*NE2);
  uint32_t* e2v     = (uint32_t*)alloc(sizeof(uint32_t)*NTET*6);
  uint32_t* part    = (uint32_t*)alloc(sizeof(uint32_t)*2048);
  if (o > ws_size) return;  // workspace too small: bail loudly (validation fails)

  k_zero2<<<(NVERT+255)/256, 256, 0, stream>>>(bincl, fill, NVERT);

  k_sdf<<<(NVERT+255)/256, 256, 0, stream>>>(ssign, sabs, sdf, occ);
  k_tet<<<(NTET+255)/256, 256, 0, stream>>>(idx, occ, tetidx, oneI, twoI, bincl);

  scan_u32(bincl, NVERT, part, stream);

  k_scatter<<<(NTET+255)/256, 256, 0, stream>>>(idx, tetidx, bincl, fill, skey);
  k_bsort<<<1024, 256, 0, stream>>>(skey, bincl);

  k_flags<<<(NE2+255)/256, 256, 0, stream>>>(skey, bincl, maskI);
  scan_u32(maskI, NE2, part, stream);
  scan_u32(oneI, NTET, part, stream);
  scan_u32(twoI, NTET, part, stream);

  k_emit<<<(NE2+255)/256, 256, 0, stream>>>(skey, maskI, bincl, verts, deform, sdf, e2v, out);
  k_faces<<<(NTET+255)/256, 256, 0, stream>>>(tetidx, oneI, twoI, maskI, e2v, out);
  k_uvs<<<(4*NG*NG+255)/256, 256, 0, stream>>>(maskI, oneI, twoI, out);
}